// Round 8
// baseline (263.011 us; speedup 1.0000x reference)
//
#include <hip/hip_runtime.h>
#include <hip/hip_bf16.h>
#include <math.h>
#include <float.h>

#define N_INST 512
#define LSEQ 512
#define EMB 128
#define NF 128
#define KW 3
#define HID 384
#define ATT 128
#define NCLS 53

#define XCOLS 66        // halo columns staged per chunk: c0-1 .. c0+64
#define XCOL_STRIDE 136 // ushorts per column (128 e + 8 pad) = 272 B, 16B-aligned

typedef __attribute__((ext_vector_type(8))) short short8;
typedef __attribute__((ext_vector_type(4))) float f32x4;

// ---------------- prep: split W into bf16 hi/lo, fragment-major; transpose W_w ----------------
// Fragment layout: idx = (((kk*4 + eb)*8 + mf8)*64 + L)*8 + i
//   A-frag (16x32): lane L supplies A[m = L&15][k = (L>>4)*8 + i]
//   f = mf8*16 + (L&15), e = eb*32 + (L>>4)*8 + i
__global__ __launch_bounds__(256) void prep_kernel(const float* __restrict__ conv_w,
                                                   const float* __restrict__ W_w,
                                                   ushort* __restrict__ whi,
                                                   ushort* __restrict__ wlo,
                                                   float* __restrict__ wwt) {
  int i = blockIdx.x * 256 + threadIdx.x;  // 0 .. 49151 exactly
  {
    int ii = i & 7;
    int L  = (i >> 3) & 63;
    int mf8 = (i >> 9) & 7;
    int eb = (i >> 12) & 3;
    int kk = (i >> 14);  // 0..2
    int f = mf8 * 16 + (L & 15);
    int e = eb * 32 + (L >> 4) * 8 + ii;
    float v = conv_w[(f * EMB + e) * KW + kk];
    __hip_bfloat16 hb = __float2bfloat16(v);
    float hf = __bfloat162float(hb);
    __hip_bfloat16 lb = __float2bfloat16(v - hf);
    whi[i] = *reinterpret_cast<ushort*>(&hb);
    wlo[i] = *reinterpret_cast<ushort*>(&lb);
  }
  {
    int a = i / HID;
    int h = i % HID;
    wwt[h * ATT + a] = W_w[i];  // wwt[h][a]
  }
}

// ---------------- fused embed + conv(MFMA) + relu + piecewise max + attn score ----------------
// grid = N_INST (1 block = 1 instance), 512 threads = 8 waves.
// Wave wv = (fg, ch2): filters [fg*32, fg*32+32) x cols [ch2*32, ch2*32+32) of each
// 64-col chunk. 8 chunks cover L=512; running segment maxes live in registers.
// No atomics, H written directly; attention score fused at the tail.
__global__ __launch_bounds__(512) void pcnn_kernel(
    const int* __restrict__ char_ids, const int* __restrict__ pos_e1,
    const int* __restrict__ pos_e2, const float* __restrict__ emb,
    const float* __restrict__ conv_b, const ushort* __restrict__ whi,
    const ushort* __restrict__ wlo, const float* __restrict__ wwt,
    const float* __restrict__ W_b, const float* __restrict__ u_w,
    float* __restrict__ H, float* __restrict__ scores) {
  __shared__ ushort xh[XCOLS * XCOL_STRIDE];  // 17.95 KB
  __shared__ ushort xl[XCOLS * XCOL_STRIDE];  // 17.95 KB
  __shared__ float smAll[2][HID];             // 3 KB: per-col-half partial maxes
  __shared__ float Hrow[HID];
  __shared__ float red2[128];

  const int n = blockIdx.x;
  const int t = threadIdx.x;
  const int wv = t >> 6;
  const int fg = wv >> 1;   // filter group: f in [fg*32, fg*32+32)
  const int ch2 = wv & 1;   // column half within chunk: cols [ch2*32, +32)
  const int L = t & 63;
  const int lc = L & 15;    // column-in-fragment
  const int lg = L >> 4;    // 4-lane group

  // per-row segment boundaries (mirrors reference)
  int p1 = pos_e1[n], p2 = pos_e2[n];
  int e1v = min(p1, p2), e2v = max(p1, p2);
  e1v = min(max(e1v, 0), LSEQ);
  e2v = min(max(e2v, 0), LSEQ);
  if (e1v == e2v) e2v = min(e1v + 1, LSEQ);
  const int end1 = (e1v > 0) ? e1v : 1;

  float biasv[2][4];
#pragma unroll
  for (int mf = 0; mf < 2; ++mf)
#pragma unroll
    for (int r = 0; r < 4; ++r)
      biasv[mf][r] = conv_b[fg * 32 + mf * 16 + lg * 4 + r];

  float sm1[2][4], sm2[2][4], sm3[2][4];
#pragma unroll
  for (int mf = 0; mf < 2; ++mf)
#pragma unroll
    for (int r = 0; r < 4; ++r) {
      sm1[mf][r] = -FLT_MAX; sm2[mf][r] = -FLT_MAX; sm3[mf][r] = -FLT_MAX;
    }

  const f32x4 zz = {0.f, 0.f, 0.f, 0.f};

  for (int ch = 0; ch < 8; ++ch) {
    const int c0 = ch * 64;
    __syncthreads();  // previous chunk's LDS reads complete before re-stage

    // ---- stage chunk: gather emb rows, split fp32 -> bf16 hi+lo, col-major ----
    {
      const int q8 = t & 7;  // e-sixteenth: e in [16*q8, 16*q8+16)
      for (int j = (t >> 3); j < XCOLS; j += 64) {
        int g = c0 - 1 + j;
        ushort* dh = xh + j * XCOL_STRIDE + q8 * 16;
        ushort* dl = xl + j * XCOL_STRIDE + q8 * 16;
        if ((unsigned)g < (unsigned)LSEQ) {
          int cid = char_ids[n * LSEQ + g];
          const float* er = emb + cid * EMB + q8 * 16;
#pragma unroll
          for (int c = 0; c < 2; ++c) {
            float4 v0 = *(const float4*)(er + c * 8);
            float4 v1 = *(const float4*)(er + c * 8 + 4);
            float vv[8] = {v0.x, v0.y, v0.z, v0.w, v1.x, v1.y, v1.z, v1.w};
            short8 hvec, lvec;
#pragma unroll
            for (int w = 0; w < 8; ++w) {
              __hip_bfloat16 hb = __float2bfloat16(vv[w]);
              float hf = __bfloat162float(hb);
              __hip_bfloat16 lb = __float2bfloat16(vv[w] - hf);
              hvec[w] = (short)*reinterpret_cast<ushort*>(&hb);
              lvec[w] = (short)*reinterpret_cast<ushort*>(&lb);
            }
            *(short8*)(dh + c * 8) = hvec;
            *(short8*)(dl + c * 8) = lvec;
          }
        } else {
          short8 z = {0, 0, 0, 0, 0, 0, 0, 0};
#pragma unroll
          for (int c = 0; c < 2; ++c) {
            *(short8*)(dh + c * 8) = z;
            *(short8*)(dl + c * 8) = z;
          }
        }
      }
    }
    __syncthreads();

    // ---- MFMA: 2 mf-frags x 2 nf-frags per wave ----
    f32x4 acc[2][2];
#pragma unroll
    for (int mf = 0; mf < 2; ++mf)
#pragma unroll
      for (int nf = 0; nf < 2; ++nf) acc[mf][nf] = zz;

    for (int eb = 0; eb < 4; ++eb) {
#pragma unroll
      for (int kk = 0; kk < 3; ++kk) {
        short8 ah[2], al[2];
#pragma unroll
        for (int mf = 0; mf < 2; ++mf) {
          int fragi = ((kk * 4 + eb) * 8 + (fg * 2 + mf)) * 64 + L;
          ah[mf] = *(const short8*)(whi + fragi * 8);
          al[mf] = *(const short8*)(wlo + fragi * 8);
        }
#pragma unroll
        for (int nf = 0; nf < 2; ++nf) {
          // output col l = c0 + ch2*32 + nf*16 + lc needs x col l+kk-1
          int off = (ch2 * 32 + nf * 16 + kk + lc) * XCOL_STRIDE + eb * 32 + lg * 8;
          short8 bh = *(const short8*)(xh + off);
          short8 bl = *(const short8*)(xl + off);
#pragma unroll
          for (int mf = 0; mf < 2; ++mf) {
            acc[mf][nf] = __builtin_amdgcn_mfma_f32_16x16x32_bf16(ah[mf], bh, acc[mf][nf], 0, 0, 0);
            acc[mf][nf] = __builtin_amdgcn_mfma_f32_16x16x32_bf16(ah[mf], bl, acc[mf][nf], 0, 0, 0);
            acc[mf][nf] = __builtin_amdgcn_mfma_f32_16x16x32_bf16(al[mf], bh, acc[mf][nf], 0, 0, 0);
          }
        }
      }
    }

    // ---- fold chunk into running segment maxes ----
#pragma unroll
    for (int mf = 0; mf < 2; ++mf)
#pragma unroll
      for (int r = 0; r < 4; ++r) {
        const float bias = biasv[mf][r];
#pragma unroll
        for (int nf = 0; nf < 2; ++nf) {
          int l = c0 + ch2 * 32 + nf * 16 + lc;
          float y = fmaxf(acc[mf][nf][r] + bias, 0.0f);
          if (l < end1) sm1[mf][r] = fmaxf(sm1[mf][r], y);
          if (l >= e1v && l < e2v) sm2[mf][r] = fmaxf(sm2[mf][r], y);
          bool in3 = (e2v < LSEQ) ? (l >= e2v) : (l == LSEQ - 1);
          if (in3) sm3[mf][r] = fmaxf(sm3[mf][r], y);
        }
      }
  }

  // ---- reduce over the 16 lc lanes, combine col-halves, write H ----
#pragma unroll
  for (int mf = 0; mf < 2; ++mf)
#pragma unroll
    for (int r = 0; r < 4; ++r) {
      float m1 = sm1[mf][r], m2 = sm2[mf][r], m3 = sm3[mf][r];
#pragma unroll
      for (int off = 1; off < 16; off <<= 1) {
        m1 = fmaxf(m1, __shfl_xor(m1, off, 64));
        m2 = fmaxf(m2, __shfl_xor(m2, off, 64));
        m3 = fmaxf(m3, __shfl_xor(m3, off, 64));
      }
      if (lc == 0) {
        int f = fg * 32 + mf * 16 + lg * 4 + r;
        smAll[ch2][0 * NF + f] = m1;
        smAll[ch2][1 * NF + f] = m2;
        smAll[ch2][2 * NF + f] = m3;
      }
    }
  __syncthreads();
  if (t < HID) {
    float v = fmaxf(smAll[0][t], smAll[1][t]);
    Hrow[t] = v;
    H[n * HID + t] = v;
  }
  __syncthreads();

  // ---- fused attention score: tanh(H . W^T + b) . u ----
  if (t < ATT) {
    float ss = W_b[t];
#pragma unroll 8
    for (int h = 0; h < HID; ++h) ss = fmaf(Hrow[h], wwt[h * ATT + t], ss);
    red2[t] = tanhf(ss) * u_w[t];
  }
  __syncthreads();
  for (int off = 64; off > 0; off >>= 1) {
    if (t < off) red2[t] += red2[t + off];
    __syncthreads();
  }
  if (t == 0) scores[n] = red2[0];
}

// ---------------- softmax over instances + bag aggregation + logits ----------------
__global__ __launch_bounds__(256) void finalize_kernel(
    const float* __restrict__ scores, const float* __restrict__ H,
    const float* __restrict__ fc_w, const float* __restrict__ fc_b,
    float* __restrict__ out) {
  __shared__ float sattn[N_INST];
  __shared__ float sred[256];
  __shared__ float hbag[HID];
  const int t = threadIdx.x;
  float s0 = scores[t];
  float s1 = scores[t + 256];
  sred[t] = fmaxf(s0, s1);
  __syncthreads();
  for (int off = 128; off > 0; off >>= 1) {
    if (t < off) sred[t] = fmaxf(sred[t], sred[t + off]);
    __syncthreads();
  }
  float mx = sred[0];
  __syncthreads();
  float ex0 = expf(s0 - mx), ex1 = expf(s1 - mx);
  sred[t] = ex0 + ex1;
  __syncthreads();
  for (int off = 128; off > 0; off >>= 1) {
    if (t < off) sred[t] += sred[t + off];
    __syncthreads();
  }
  float inv = 1.0f / sred[0];
  float a0 = ex0 * inv, a1 = ex1 * inv;
  sattn[t] = a0;
  sattn[t + 256] = a1;
  out[NCLS + t] = a0;
  out[NCLS + 256 + t] = a1;
  __syncthreads();

  for (int cc = t; cc < HID; cc += 256) {
    float acc = 0.0f;
    for (int n2 = 0; n2 < N_INST; ++n2) acc = fmaf(sattn[n2], H[n2 * HID + cc], acc);
    hbag[cc] = acc;
  }
  __syncthreads();
  if (t < NCLS) {
    float acc = fc_b[t];
    for (int h = 0; h < HID; ++h) acc = fmaf(hbag[h], fc_w[t * HID + h], acc);
    out[t] = acc;
  }
}

extern "C" void kernel_launch(void* const* d_in, const int* in_sizes, int n_in,
                              void* d_out, int out_size, void* d_ws, size_t ws_size,
                              hipStream_t stream) {
  const int* char_ids = (const int*)d_in[0];
  const int* pos_e1 = (const int*)d_in[1];
  const int* pos_e2 = (const int*)d_in[2];
  const float* emb = (const float*)d_in[3];
  const float* conv_w = (const float*)d_in[4];
  const float* conv_b = (const float*)d_in[5];
  const float* W_w = (const float*)d_in[6];
  const float* W_b = (const float*)d_in[7];
  const float* u_w = (const float*)d_in[8];
  const float* fc_w = (const float*)d_in[9];
  const float* fc_b = (const float*)d_in[10];
  float* out = (float*)d_out;

  ushort* whi = (ushort*)d_ws;                  // 49152 ushorts
  ushort* wlo = whi + NF * EMB * KW;            // 49152 ushorts
  float* wwt = (float*)(wlo + NF * EMB * KW);   // 49152 floats (16B-aligned offset)
  float* H = wwt + ATT * HID;                   // 196608 floats
  float* scores = H + N_INST * HID;             // 512 floats

  hipLaunchKernelGGL(prep_kernel, dim3(192), dim3(256), 0, stream, conv_w, W_w, whi, wlo, wwt);
  hipLaunchKernelGGL(pcnn_kernel, dim3(N_INST), dim3(512), 0, stream,
                     char_ids, pos_e1, pos_e2, emb, conv_b, whi, wlo, wwt, W_b, u_w, H, scores);
  hipLaunchKernelGGL(finalize_kernel, dim3(1), dim3(256), 0, stream, scores, H, fc_w, fc_b, out);
}